// Round 1
// baseline (3400.559 us; speedup 1.0000x reference)
//
#include <hip/hip_runtime.h>
#include <math.h>

#define N_NODES 50000
#define E_RAW   800000
#define E_TOT   850000
#define NEG_SLOPE 0.2f

__device__ __forceinline__ float lrelu(float v) {
    return v >= 0.f ? v : NEG_SLOPE * v;
}

// ---------------------------------------------------------------------------
// K1: h1 = x @ W1  ([50000,256]@[256,256]) + per-head attention dots
//     as1[n,h] = sum_c h1[n,h*64+c]*att_src[h,c]   (same for ad1)
// Block: 256 threads, 32 rows. Thread (jg=t&63, rg=t>>6) owns cols jg*4..+3,
// rows rg*8..+7. Wave w = rows w*8..w*8+7, all 256 cols; head = jg>>4 so each
// 16-lane group covers exactly one head -> shfl_xor(1,2,4,8) reduction.
// ---------------------------------------------------------------------------
__global__ __launch_bounds__(256) void k_gemm1(
    const float* __restrict__ x, const float* __restrict__ W1,
    const float* __restrict__ att_src, const float* __restrict__ att_dst,
    float* __restrict__ h1, float* __restrict__ as1, float* __restrict__ ad1)
{
    __shared__ float xs[32 * 256];
    const int t = threadIdx.x;
    const int n0 = blockIdx.x * 32;
    for (int i = t; i < 32 * 256; i += 256) {
        int n = n0 + (i >> 8);
        xs[i] = (n < N_NODES) ? x[n * 256 + (i & 255)] : 0.f;
    }
    __syncthreads();
    const int jg = t & 63;
    const int rg = t >> 6;
    const int col0 = jg * 4;
    float acc[8][4];
#pragma unroll
    for (int r = 0; r < 8; ++r)
#pragma unroll
        for (int c = 0; c < 4; ++c) acc[r][c] = 0.f;

    for (int k = 0; k < 256; k += 4) {
        float4 w0 = *(const float4*)&W1[(k + 0) * 256 + col0];
        float4 w1 = *(const float4*)&W1[(k + 1) * 256 + col0];
        float4 w2 = *(const float4*)&W1[(k + 2) * 256 + col0];
        float4 w3 = *(const float4*)&W1[(k + 3) * 256 + col0];
#pragma unroll
        for (int r = 0; r < 8; ++r) {
            float4 xv = *(const float4*)&xs[(rg * 8 + r) * 256 + k];
            acc[r][0] = fmaf(xv.x, w0.x, fmaf(xv.y, w1.x, fmaf(xv.z, w2.x, fmaf(xv.w, w3.x, acc[r][0]))));
            acc[r][1] = fmaf(xv.x, w0.y, fmaf(xv.y, w1.y, fmaf(xv.z, w2.y, fmaf(xv.w, w3.y, acc[r][1]))));
            acc[r][2] = fmaf(xv.x, w0.z, fmaf(xv.y, w1.z, fmaf(xv.z, w2.z, fmaf(xv.w, w3.z, acc[r][2]))));
            acc[r][3] = fmaf(xv.x, w0.w, fmaf(xv.y, w1.w, fmaf(xv.z, w2.w, fmaf(xv.w, w3.w, acc[r][3]))));
        }
    }
    const int head = jg >> 4;
    const int cih  = (jg & 15) * 4;
    float asv[4], adv[4];
#pragma unroll
    for (int c = 0; c < 4; ++c) {
        asv[c] = att_src[head * 64 + cih + c];
        adv[c] = att_dst[head * 64 + cih + c];
    }
#pragma unroll
    for (int r = 0; r < 8; ++r) {
        const int n = n0 + rg * 8 + r;
        float ps = acc[r][0]*asv[0] + acc[r][1]*asv[1] + acc[r][2]*asv[2] + acc[r][3]*asv[3];
        float pd = acc[r][0]*adv[0] + acc[r][1]*adv[1] + acc[r][2]*adv[2] + acc[r][3]*adv[3];
#pragma unroll
        for (int off = 1; off < 16; off <<= 1) {
            ps += __shfl_xor(ps, off);
            pd += __shfl_xor(pd, off);
        }
        if (n < N_NODES) {
            if ((jg & 15) == 0) {
                as1[n * 4 + head] = ps;
                ad1[n * 4 + head] = pd;
            }
            *(float4*)&h1[n * 256 + col0] =
                make_float4(acc[r][0], acc[r][1], acc[r][2], acc[r][3]);
        }
    }
}

// ---------------------------------------------------------------------------
// K2: denom1[d,h] += exp(lrelu(as1[s,h]+ad1[d,h]))  -- thread per edge.
// Softmax max-subtraction skipped: shift-invariant, logits O(10), f32 safe.
// ---------------------------------------------------------------------------
__global__ __launch_bounds__(256) void k_denom1(
    const int* __restrict__ src, const int* __restrict__ dst,
    const float* __restrict__ as1, const float* __restrict__ ad1,
    float* __restrict__ denom1)
{
    int e = blockIdx.x * 256 + threadIdx.x;
    if (e >= E_TOT) return;
    int s, d;
    if (e < E_RAW) { s = src[e]; d = dst[e]; } else { s = e - E_RAW; d = s; }
    float4 a = *(const float4*)&as1[s * 4];
    float4 b = *(const float4*)&ad1[d * 4];
    atomicAdd(&denom1[d * 4 + 0], __expf(lrelu(a.x + b.x)));
    atomicAdd(&denom1[d * 4 + 1], __expf(lrelu(a.y + b.y)));
    atomicAdd(&denom1[d * 4 + 2], __expf(lrelu(a.z + b.z)));
    atomicAdd(&denom1[d * 4 + 3], __expf(lrelu(a.w + b.w)));
}

// ---------------------------------------------------------------------------
// K3: agg1[d,:] += alpha * h1[s,:]  -- wave per edge, lane owns cols l*4..+3
// (head = l>>4). 1KB coalesced gather + 4 scalar atomics/lane.
// ---------------------------------------------------------------------------
__global__ __launch_bounds__(256) void k_agg1(
    const int* __restrict__ src, const int* __restrict__ dst,
    const float* __restrict__ as1, const float* __restrict__ ad1,
    const float* __restrict__ denom1, const float* __restrict__ h1,
    float* __restrict__ agg1)
{
    int wid  = (blockIdx.x * 256 + threadIdx.x) >> 6;
    int lane = threadIdx.x & 63;
    if (wid >= E_TOT) return;
    int s, d;
    if (wid < E_RAW) { s = src[wid]; d = dst[wid]; } else { s = wid - E_RAW; d = s; }
    int head = lane >> 4;
    float ee = lrelu(as1[s * 4 + head] + ad1[d * 4 + head]);
    float alpha = __expf(ee) / (denom1[d * 4 + head] + 1e-16f);
    float4 v = *(const float4*)&h1[s * 256 + lane * 4];
    float* o = &agg1[d * 256 + lane * 4];
    atomicAdd(o + 0, alpha * v.x);
    atomicAdd(o + 1, alpha * v.y);
    atomicAdd(o + 2, alpha * v.z);
    atomicAdd(o + 3, alpha * v.w);
}

// K4: h = elu(agg1 + b1), in place.
__global__ __launch_bounds__(256) void k_bias_elu(
    float* __restrict__ h, const float* __restrict__ b1)
{
    int i = blockIdx.x * 256 + threadIdx.x;
    if (i >= N_NODES * 256) return;
    float v = h[i] + b1[i & 255];
    h[i] = v > 0.f ? v : expm1f(v);
}

// ---------------------------------------------------------------------------
// K5: h2 = h @ W2 ([50000,256]@[256,64]) + single-head attention dots.
// Block: 256 threads, 64 rows. Thread (jg=t&15, rg=t>>4) owns cols jg*4..+3,
// rows rg + {0,16,32,48}. LDS padded to 264 floats/row: consecutive rg rows
// differ by 8 banks -> 4 distinct rows hit banks {0,8,16,24}, conflict-free.
// ---------------------------------------------------------------------------
__global__ __launch_bounds__(256) void k_gemm2(
    const float* __restrict__ h, const float* __restrict__ W2,
    const float* __restrict__ att_src, const float* __restrict__ att_dst,
    float* __restrict__ h2, float* __restrict__ as2, float* __restrict__ ad2)
{
    __shared__ float hs[64 * 264];
    const int t = threadIdx.x;
    const int n0 = blockIdx.x * 64;
#pragma unroll
    for (int it = 0; it < 16; ++it) {
        int linear = it * 1024 + t * 4;
        int r = linear >> 8, c = linear & 255;
        int n = n0 + r;
        float4 v = make_float4(0.f, 0.f, 0.f, 0.f);
        if (n < N_NODES) v = *(const float4*)&h[n * 256 + c];
        *(float4*)&hs[r * 264 + c] = v;
    }
    __syncthreads();
    const int jg = t & 15, rg = t >> 4;
    const int col0 = jg * 4;
    float acc[4][4];
#pragma unroll
    for (int r = 0; r < 4; ++r)
#pragma unroll
        for (int c = 0; c < 4; ++c) acc[r][c] = 0.f;

    for (int k = 0; k < 256; k += 4) {
        float4 w0 = *(const float4*)&W2[(k + 0) * 64 + col0];
        float4 w1 = *(const float4*)&W2[(k + 1) * 64 + col0];
        float4 w2 = *(const float4*)&W2[(k + 2) * 64 + col0];
        float4 w3 = *(const float4*)&W2[(k + 3) * 64 + col0];
#pragma unroll
        for (int r = 0; r < 4; ++r) {
            float4 xv = *(const float4*)&hs[(rg + 16 * r) * 264 + k];
            acc[r][0] = fmaf(xv.x, w0.x, fmaf(xv.y, w1.x, fmaf(xv.z, w2.x, fmaf(xv.w, w3.x, acc[r][0]))));
            acc[r][1] = fmaf(xv.x, w0.y, fmaf(xv.y, w1.y, fmaf(xv.z, w2.y, fmaf(xv.w, w3.y, acc[r][1]))));
            acc[r][2] = fmaf(xv.x, w0.z, fmaf(xv.y, w1.z, fmaf(xv.z, w2.z, fmaf(xv.w, w3.z, acc[r][2]))));
            acc[r][3] = fmaf(xv.x, w0.w, fmaf(xv.y, w1.w, fmaf(xv.z, w2.w, fmaf(xv.w, w3.w, acc[r][3]))));
        }
    }
    float asv[4], adv[4];
#pragma unroll
    for (int c = 0; c < 4; ++c) {
        asv[c] = att_src[col0 + c];
        adv[c] = att_dst[col0 + c];
    }
#pragma unroll
    for (int r = 0; r < 4; ++r) {
        const int n = n0 + rg + 16 * r;
        float ps = acc[r][0]*asv[0] + acc[r][1]*asv[1] + acc[r][2]*asv[2] + acc[r][3]*asv[3];
        float pd = acc[r][0]*adv[0] + acc[r][1]*adv[1] + acc[r][2]*adv[2] + acc[r][3]*adv[3];
#pragma unroll
        for (int off = 1; off < 16; off <<= 1) {
            ps += __shfl_xor(ps, off);
            pd += __shfl_xor(pd, off);
        }
        if (n < N_NODES) {
            if (jg == 0) { as2[n] = ps; ad2[n] = pd; }
            *(float4*)&h2[n * 64 + col0] =
                make_float4(acc[r][0], acc[r][1], acc[r][2], acc[r][3]);
        }
    }
}

// K6: denom2[d] += exp(lrelu(as2[s]+ad2[d]))
__global__ __launch_bounds__(256) void k_denom2(
    const int* __restrict__ src, const int* __restrict__ dst,
    const float* __restrict__ as2, const float* __restrict__ ad2,
    float* __restrict__ denom2)
{
    int e = blockIdx.x * 256 + threadIdx.x;
    if (e >= E_TOT) return;
    int s, d;
    if (e < E_RAW) { s = src[e]; d = dst[e]; } else { s = e - E_RAW; d = s; }
    atomicAdd(&denom2[d], __expf(lrelu(as2[s] + ad2[d])));
}

// K7: agg2[d,:] += alpha * h2[s,:]  -- wave per edge, lane = col (C=64).
__global__ __launch_bounds__(256) void k_agg2(
    const int* __restrict__ src, const int* __restrict__ dst,
    const float* __restrict__ as2, const float* __restrict__ ad2,
    const float* __restrict__ denom2, const float* __restrict__ h2,
    float* __restrict__ agg2)
{
    int wid  = (blockIdx.x * 256 + threadIdx.x) >> 6;
    int lane = threadIdx.x & 63;
    if (wid >= E_TOT) return;
    int s, d;
    if (wid < E_RAW) { s = src[wid]; d = dst[wid]; } else { s = wid - E_RAW; d = s; }
    float ee = lrelu(as2[s] + ad2[d]);
    float alpha = __expf(ee) / (denom2[d] + 1e-16f);
    float v = h2[s * 64 + lane];
    atomicAdd(&agg2[d * 64 + lane], alpha * v);
}

// K8: out = agg2 + b2
__global__ __launch_bounds__(256) void k_out(
    const float* __restrict__ agg2, const float* __restrict__ b2,
    float* __restrict__ out)
{
    int i = blockIdx.x * 256 + threadIdx.x;
    if (i >= N_NODES * 64) return;
    out[i] = agg2[i] + b2[i & 63];
}

// ---------------------------------------------------------------------------
// Workspace layout (bytes), total requirement 105,400,000:
//   agg1   @ 0           51,200,000   (zeroed, memset #1 covers 0..52.2M)
//   denom1 @ 51,200,000     800,000
//   denom2 @ 52,000,000     200,000
//   as1    @ 52,200,000     800,000
//   ad1    @ 53,000,000     800,000
//   as2    @ 53,800,000     200,000
//   ad2    @ 54,000,000     200,000
//   h1     @ 54,200,000  51,200,000   (dead after K3; region reused:)
//   h2     @ 54,200,000  12,800,000
//   agg2   @ 67,000,000  12,800,000   (zeroed by memset #2 after K4)
// ---------------------------------------------------------------------------
extern "C" void kernel_launch(void* const* d_in, const int* in_sizes, int n_in,
                              void* d_out, int out_size, void* d_ws, size_t ws_size,
                              hipStream_t stream)
{
    const float* x        = (const float*)d_in[0];
    const int*   ei       = (const int*)d_in[1];
    const float* W1       = (const float*)d_in[2];
    const float* att_src1 = (const float*)d_in[3];
    const float* att_dst1 = (const float*)d_in[4];
    const float* b1       = (const float*)d_in[5];
    const float* W2       = (const float*)d_in[6];
    const float* att_src2 = (const float*)d_in[7];
    const float* att_dst2 = (const float*)d_in[8];
    const float* b2       = (const float*)d_in[9];
    const int* src = ei;
    const int* dst = ei + E_RAW;
    float* out = (float*)d_out;

    char* ws = (char*)d_ws;
    float* agg1   = (float*)(ws + 0);
    float* denom1 = (float*)(ws + 51200000);
    float* denom2 = (float*)(ws + 52000000);
    float* as1    = (float*)(ws + 52200000);
    float* ad1    = (float*)(ws + 53000000);
    float* as2    = (float*)(ws + 53800000);
    float* ad2    = (float*)(ws + 54000000);
    float* h1     = (float*)(ws + 54200000);
    float* h2     = (float*)(ws + 54200000);   // reuses h1 region
    float* agg2   = (float*)(ws + 67000000);   // reuses h1 region

    // zero agg1 + denom1 + denom2 (contiguous)
    hipMemsetAsync(ws, 0, 52200000, stream);

    k_gemm1 <<<1563, 256, 0, stream>>>(x, W1, att_src1, att_dst1, h1, as1, ad1);
    k_denom1<<<(E_TOT + 255) / 256, 256, 0, stream>>>(src, dst, as1, ad1, denom1);
    k_agg1  <<<E_TOT / 4, 256, 0, stream>>>(src, dst, as1, ad1, denom1, h1, agg1);
    k_bias_elu<<<N_NODES, 256, 0, stream>>>(agg1, b1);

    // zero agg2 (h1 region now dead)
    hipMemsetAsync(ws + 67000000, 0, 12800000, stream);

    k_gemm2 <<<782, 256, 0, stream>>>(agg1, W2, att_src2, att_dst2, h2, as2, ad2);
    k_denom2<<<(E_TOT + 255) / 256, 256, 0, stream>>>(src, dst, as2, ad2, denom2);
    k_agg2  <<<E_TOT / 4, 256, 0, stream>>>(src, dst, as2, ad2, denom2, h2, agg2);
    k_out   <<<N_NODES * 64 / 256, 256, 0, stream>>>(agg2, b2, out);
}

// Round 2
// 508.738 us; speedup vs baseline: 6.6843x; 6.6843x over previous
//
#include <hip/hip_runtime.h>
#include <math.h>

#define N_NODES 50000
#define E_RAW   800000
#define E_TOT   850000
#define NEG_SLOPE 0.2f

__device__ __forceinline__ float lrelu(float v) {
    return v >= 0.f ? v : NEG_SLOPE * v;
}

// ---------------------------------------------------------------------------
// CSR build: histogram -> scan -> scatter. Int atomics only (~1.7M total),
// all on small L2-resident arrays.
// ---------------------------------------------------------------------------
__global__ __launch_bounds__(256) void k_hist(
    const int* __restrict__ dst, int* __restrict__ counts)
{
    int e = blockIdx.x * 256 + threadIdx.x;
    if (e >= E_TOT) return;
    int d = (e < E_RAW) ? dst[e] : e - E_RAW;
    atomicAdd(&counts[d], 1);
}

// Single block, 1024 threads: thread t serially sums its 49-elem chunk,
// Hillis-Steele scan of the 1024 partials in LDS, then writes exclusive
// prefix per element. off[N_NODES] = E_TOT written by last thread.
__global__ __launch_bounds__(1024) void k_scan(
    const int* __restrict__ counts, int* __restrict__ off)
{
    __shared__ int part[1024];
    const int tid = threadIdx.x;
    const int CH = (N_NODES + 1023) / 1024;           // 49
    const int lo = tid * CH;
    const int hi = (lo + CH < N_NODES) ? lo + CH : N_NODES;
    int s = 0;
    for (int i = lo; i < hi; ++i) s += counts[i];
    part[tid] = s;
    __syncthreads();
    for (int ofs = 1; ofs < 1024; ofs <<= 1) {
        int v = (tid >= ofs) ? part[tid - ofs] : 0;
        __syncthreads();
        part[tid] += v;
        __syncthreads();
    }
    int run = part[tid] - s;                          // exclusive base
    for (int i = lo; i < hi; ++i) { off[i] = run; run += counts[i]; }
    if (tid == 1023) off[N_NODES] = part[1023];
}

__global__ __launch_bounds__(256) void k_scatter(
    const int* __restrict__ src, const int* __restrict__ dst,
    const int* __restrict__ off, int* __restrict__ cursor,
    int* __restrict__ esrc)
{
    int e = blockIdx.x * 256 + threadIdx.x;
    if (e >= E_TOT) return;
    int s, d;
    if (e < E_RAW) { s = src[e]; d = dst[e]; } else { s = e - E_RAW; d = s; }
    int pos = off[d] + atomicAdd(&cursor[d], 1);
    esrc[pos] = s;
}

// ---------------------------------------------------------------------------
// K1: h1 = x @ W1  ([50000,256]@[256,256]) + per-head attention dots.
// (unchanged from round 1 -- correct, not yet the bottleneck)
// ---------------------------------------------------------------------------
__global__ __launch_bounds__(256) void k_gemm1(
    const float* __restrict__ x, const float* __restrict__ W1,
    const float* __restrict__ att_src, const float* __restrict__ att_dst,
    float* __restrict__ h1, float* __restrict__ as1, float* __restrict__ ad1)
{
    __shared__ float xs[32 * 256];
    const int t = threadIdx.x;
    const int n0 = blockIdx.x * 32;
    for (int i = t; i < 32 * 256; i += 256) {
        int n = n0 + (i >> 8);
        xs[i] = (n < N_NODES) ? x[n * 256 + (i & 255)] : 0.f;
    }
    __syncthreads();
    const int jg = t & 63;
    const int rg = t >> 6;
    const int col0 = jg * 4;
    float acc[8][4];
#pragma unroll
    for (int r = 0; r < 8; ++r)
#pragma unroll
        for (int c = 0; c < 4; ++c) acc[r][c] = 0.f;

    for (int k = 0; k < 256; k += 4) {
        float4 w0 = *(const float4*)&W1[(k + 0) * 256 + col0];
        float4 w1 = *(const float4*)&W1[(k + 1) * 256 + col0];
        float4 w2 = *(const float4*)&W1[(k + 2) * 256 + col0];
        float4 w3 = *(const float4*)&W1[(k + 3) * 256 + col0];
#pragma unroll
        for (int r = 0; r < 8; ++r) {
            float4 xv = *(const float4*)&xs[(rg * 8 + r) * 256 + k];
            acc[r][0] = fmaf(xv.x, w0.x, fmaf(xv.y, w1.x, fmaf(xv.z, w2.x, fmaf(xv.w, w3.x, acc[r][0]))));
            acc[r][1] = fmaf(xv.x, w0.y, fmaf(xv.y, w1.y, fmaf(xv.z, w2.y, fmaf(xv.w, w3.y, acc[r][1]))));
            acc[r][2] = fmaf(xv.x, w0.z, fmaf(xv.y, w1.z, fmaf(xv.z, w2.z, fmaf(xv.w, w3.z, acc[r][2]))));
            acc[r][3] = fmaf(xv.x, w0.w, fmaf(xv.y, w1.w, fmaf(xv.z, w2.w, fmaf(xv.w, w3.w, acc[r][3]))));
        }
    }
    const int head = jg >> 4;
    const int cih  = (jg & 15) * 4;
    float asv[4], adv[4];
#pragma unroll
    for (int c = 0; c < 4; ++c) {
        asv[c] = att_src[head * 64 + cih + c];
        adv[c] = att_dst[head * 64 + cih + c];
    }
#pragma unroll
    for (int r = 0; r < 8; ++r) {
        const int n = n0 + rg * 8 + r;
        float ps = acc[r][0]*asv[0] + acc[r][1]*asv[1] + acc[r][2]*asv[2] + acc[r][3]*asv[3];
        float pd = acc[r][0]*adv[0] + acc[r][1]*adv[1] + acc[r][2]*adv[2] + acc[r][3]*adv[3];
#pragma unroll
        for (int off = 1; off < 16; off <<= 1) {
            ps += __shfl_xor(ps, off);
            pd += __shfl_xor(pd, off);
        }
        if (n < N_NODES) {
            if ((jg & 15) == 0) {
                as1[n * 4 + head] = ps;
                ad1[n * 4 + head] = pd;
            }
            *(float4*)&h1[n * 256 + col0] =
                make_float4(acc[r][0], acc[r][1], acc[r][2], acc[r][3]);
        }
    }
}

// ---------------------------------------------------------------------------
// K2: fused softmax + aggregate + bias + ELU for layer 1, gather form.
// One wave per dst node; lane owns cols lane*4..+3 (head = lane>>4).
// out[d] = elu( (sum_e w_e * h1[src_e]) / (sum_e w_e) + b1 ),
// w_e = exp(lrelu(as1[s]+ad1[d])).  Zero float atomics.
// ---------------------------------------------------------------------------
__global__ __launch_bounds__(256) void k_gather1(
    const int* __restrict__ esrc, const int* __restrict__ off,
    const float* __restrict__ as1, const float* __restrict__ ad1,
    const float* __restrict__ h1, const float* __restrict__ b1,
    float* __restrict__ hmid)
{
    int d    = (blockIdx.x * 256 + threadIdx.x) >> 6;
    int lane = threadIdx.x & 63;
    if (d >= N_NODES) return;
    const int head = lane >> 4;
    const float adv = ad1[d * 4 + head];
    const int e0 = off[d], e1 = off[d + 1];
    float4 acc = make_float4(0.f, 0.f, 0.f, 0.f);
    float dn = 0.f;
    int e = e0;
    for (; e + 1 < e1; e += 2) {                      // 2x unroll for MLP
        int s0 = esrc[e], s1 = esrc[e + 1];
        float w0 = __expf(lrelu(as1[s0 * 4 + head] + adv));
        float w1 = __expf(lrelu(as1[s1 * 4 + head] + adv));
        float4 v0 = *(const float4*)&h1[s0 * 256 + lane * 4];
        float4 v1 = *(const float4*)&h1[s1 * 256 + lane * 4];
        dn += w0 + w1;
        acc.x = fmaf(w0, v0.x, fmaf(w1, v1.x, acc.x));
        acc.y = fmaf(w0, v0.y, fmaf(w1, v1.y, acc.y));
        acc.z = fmaf(w0, v0.z, fmaf(w1, v1.z, acc.z));
        acc.w = fmaf(w0, v0.w, fmaf(w1, v1.w, acc.w));
    }
    if (e < e1) {
        int s0 = esrc[e];
        float w0 = __expf(lrelu(as1[s0 * 4 + head] + adv));
        float4 v0 = *(const float4*)&h1[s0 * 256 + lane * 4];
        dn += w0;
        acc.x = fmaf(w0, v0.x, acc.x);
        acc.y = fmaf(w0, v0.y, acc.y);
        acc.z = fmaf(w0, v0.z, acc.z);
        acc.w = fmaf(w0, v0.w, acc.w);
    }
    const float inv = 1.f / (dn + 1e-16f);
    float4 bb = *(const float4*)&b1[lane * 4];
    float o0 = acc.x * inv + bb.x;
    float o1 = acc.y * inv + bb.y;
    float o2 = acc.z * inv + bb.z;
    float o3 = acc.w * inv + bb.w;
    o0 = o0 > 0.f ? o0 : expm1f(o0);
    o1 = o1 > 0.f ? o1 : expm1f(o1);
    o2 = o2 > 0.f ? o2 : expm1f(o2);
    o3 = o3 > 0.f ? o3 : expm1f(o3);
    *(float4*)&hmid[d * 256 + lane * 4] = make_float4(o0, o1, o2, o3);
}

// ---------------------------------------------------------------------------
// K3: h2 = hmid @ W2 ([50000,256]@[256,64]) + single-head attention dots.
// (unchanged from round 1)
// ---------------------------------------------------------------------------
__global__ __launch_bounds__(256) void k_gemm2(
    const float* __restrict__ h, const float* __restrict__ W2,
    const float* __restrict__ att_src, const float* __restrict__ att_dst,
    float* __restrict__ h2, float* __restrict__ as2, float* __restrict__ ad2)
{
    __shared__ float hs[64 * 264];
    const int t = threadIdx.x;
    const int n0 = blockIdx.x * 64;
#pragma unroll
    for (int it = 0; it < 16; ++it) {
        int linear = it * 1024 + t * 4;
        int r = linear >> 8, c = linear & 255;
        int n = n0 + r;
        float4 v = make_float4(0.f, 0.f, 0.f, 0.f);
        if (n < N_NODES) v = *(const float4*)&h[n * 256 + c];
        *(float4*)&hs[r * 264 + c] = v;
    }
    __syncthreads();
    const int jg = t & 15, rg = t >> 4;
    const int col0 = jg * 4;
    float acc[4][4];
#pragma unroll
    for (int r = 0; r < 4; ++r)
#pragma unroll
        for (int c = 0; c < 4; ++c) acc[r][c] = 0.f;

    for (int k = 0; k < 256; k += 4) {
        float4 w0 = *(const float4*)&W2[(k + 0) * 64 + col0];
        float4 w1 = *(const float4*)&W2[(k + 1) * 64 + col0];
        float4 w2 = *(const float4*)&W2[(k + 2) * 64 + col0];
        float4 w3 = *(const float4*)&W2[(k + 3) * 64 + col0];
#pragma unroll
        for (int r = 0; r < 4; ++r) {
            float4 xv = *(const float4*)&hs[(rg + 16 * r) * 264 + k];
            acc[r][0] = fmaf(xv.x, w0.x, fmaf(xv.y, w1.x, fmaf(xv.z, w2.x, fmaf(xv.w, w3.x, acc[r][0]))));
            acc[r][1] = fmaf(xv.x, w0.y, fmaf(xv.y, w1.y, fmaf(xv.z, w2.y, fmaf(xv.w, w3.y, acc[r][1]))));
            acc[r][2] = fmaf(xv.x, w0.z, fmaf(xv.y, w1.z, fmaf(xv.z, w2.z, fmaf(xv.w, w3.z, acc[r][2]))));
            acc[r][3] = fmaf(xv.x, w0.w, fmaf(xv.y, w1.w, fmaf(xv.z, w2.w, fmaf(xv.w, w3.w, acc[r][3]))));
        }
    }
    float asv[4], adv[4];
#pragma unroll
    for (int c = 0; c < 4; ++c) {
        asv[c] = att_src[col0 + c];
        adv[c] = att_dst[col0 + c];
    }
#pragma unroll
    for (int r = 0; r < 4; ++r) {
        const int n = n0 + rg + 16 * r;
        float ps = acc[r][0]*asv[0] + acc[r][1]*asv[1] + acc[r][2]*asv[2] + acc[r][3]*asv[3];
        float pd = acc[r][0]*adv[0] + acc[r][1]*adv[1] + acc[r][2]*adv[2] + acc[r][3]*adv[3];
#pragma unroll
        for (int off = 1; off < 16; off <<= 1) {
            ps += __shfl_xor(ps, off);
            pd += __shfl_xor(pd, off);
        }
        if (n < N_NODES) {
            if (jg == 0) { as2[n] = ps; ad2[n] = pd; }
            *(float4*)&h2[n * 64 + col0] =
                make_float4(acc[r][0], acc[r][1], acc[r][2], acc[r][3]);
        }
    }
}

// ---------------------------------------------------------------------------
// K4: fused softmax + aggregate + bias for layer 2, gather form.
// One wave per dst; lane owns one col (C=64). Writes d_out directly.
// ---------------------------------------------------------------------------
__global__ __launch_bounds__(256) void k_gather2(
    const int* __restrict__ esrc, const int* __restrict__ off,
    const float* __restrict__ as2, const float* __restrict__ ad2,
    const float* __restrict__ h2, const float* __restrict__ b2,
    float* __restrict__ out)
{
    int d    = (blockIdx.x * 256 + threadIdx.x) >> 6;
    int lane = threadIdx.x & 63;
    if (d >= N_NODES) return;
    const float adv = ad2[d];
    const int e0 = off[d], e1 = off[d + 1];
    float acc = 0.f, dn = 0.f;
    int e = e0;
    for (; e + 1 < e1; e += 2) {
        int s0 = esrc[e], s1 = esrc[e + 1];
        float w0 = __expf(lrelu(as2[s0] + adv));
        float w1 = __expf(lrelu(as2[s1] + adv));
        float v0 = h2[s0 * 64 + lane];
        float v1 = h2[s1 * 64 + lane];
        dn += w0 + w1;
        acc = fmaf(w0, v0, fmaf(w1, v1, acc));
    }
    if (e < e1) {
        int s0 = esrc[e];
        float w0 = __expf(lrelu(as2[s0] + adv));
        float v0 = h2[s0 * 64 + lane];
        dn += w0;
        acc = fmaf(w0, v0, acc);
    }
    out[d * 64 + lane] = acc / (dn + 1e-16f) + b2[lane];
}

// ---------------------------------------------------------------------------
// Workspace layout (bytes), total 108,500,000:
//   counts @ 0          200,000  [zeroed]
//   cursor @ 200,000    200,000  [zeroed]
//   off    @ 400,000    200,004
//   as1    @ 700,000    800,000
//   ad1    @ 1,500,000  800,000
//   as2    @ 2,300,000  200,000
//   ad2    @ 2,500,000  200,000
//   esrc   @ 2,700,000  3,400,000
//   h1     @ 6,100,000  51,200,000   (dead after gather1; h2 reuses it)
//   h2     @ 6,100,000  12,800,000
//   hmid   @ 57,300,000 51,200,000
// ---------------------------------------------------------------------------
extern "C" void kernel_launch(void* const* d_in, const int* in_sizes, int n_in,
                              void* d_out, int out_size, void* d_ws, size_t ws_size,
                              hipStream_t stream)
{
    const float* x        = (const float*)d_in[0];
    const int*   ei       = (const int*)d_in[1];
    const float* W1       = (const float*)d_in[2];
    const float* att_src1 = (const float*)d_in[3];
    const float* att_dst1 = (const float*)d_in[4];
    const float* b1       = (const float*)d_in[5];
    const float* W2       = (const float*)d_in[6];
    const float* att_src2 = (const float*)d_in[7];
    const float* att_dst2 = (const float*)d_in[8];
    const float* b2       = (const float*)d_in[9];
    const int* src = ei;
    const int* dst = ei + E_RAW;
    float* out = (float*)d_out;

    char* ws = (char*)d_ws;
    int*   counts = (int*)(ws + 0);
    int*   cursor = (int*)(ws + 200000);
    int*   off    = (int*)(ws + 400000);
    float* as1    = (float*)(ws + 700000);
    float* ad1    = (float*)(ws + 1500000);
    float* as2    = (float*)(ws + 2300000);
    float* ad2    = (float*)(ws + 2500000);
    int*   esrc   = (int*)(ws + 2700000);
    float* h1     = (float*)(ws + 6100000);
    float* h2     = (float*)(ws + 6100000);     // reuses h1 region
    float* hmid   = (float*)(ws + 57300000);

    hipMemsetAsync(ws, 0, 400000, stream);      // counts + cursor

    const int EB = (E_TOT + 255) / 256;
    k_hist   <<<EB, 256, 0, stream>>>(dst, counts);
    k_scan   <<<1, 1024, 0, stream>>>(counts, off);
    k_scatter<<<EB, 256, 0, stream>>>(src, dst, off, cursor, esrc);

    k_gemm1  <<<1563, 256, 0, stream>>>(x, W1, att_src1, att_dst1, h1, as1, ad1);
    k_gather1<<<12500, 256, 0, stream>>>(esrc, off, as1, ad1, h1, b1, hmid);
    k_gemm2  <<<782, 256, 0, stream>>>(hmid, W2, att_src2, att_dst2, h2, as2, ad2);
    k_gather2<<<12500, 256, 0, stream>>>(esrc, off, as2, ad2, h2, b2, out);
}

// Round 3
// 442.371 us; speedup vs baseline: 7.6871x; 1.1500x over previous
//
#include <hip/hip_runtime.h>
#include <math.h>

#define N_NODES 50000
#define E_RAW   800000
#define E_TOT   850000
#define NEG_SLOPE 0.2f

__device__ __forceinline__ float lrelu(float v) {
    return v >= 0.f ? v : NEG_SLOPE * v;
}
// f32 -> bf16 (RNE) and back, on raw ushort storage (values always finite here).
__device__ __forceinline__ unsigned short f2bf(float f) {
    union { float f; unsigned u; } v; v.f = f;
    unsigned r = v.u + 0x7FFF + ((v.u >> 16) & 1);
    return (unsigned short)(r >> 16);
}
__device__ __forceinline__ float bf2f(unsigned short h) {
    union { unsigned u; float f; } v; v.u = ((unsigned)h) << 16;
    return v.f;
}

// ---------------------------------------------------------------------------
// CSR build: histogram -> scan -> scatter. Int atomics only.
// ---------------------------------------------------------------------------
__global__ __launch_bounds__(256) void k_hist(
    const int* __restrict__ dst, int* __restrict__ counts)
{
    int e = blockIdx.x * 256 + threadIdx.x;
    if (e >= E_TOT) return;
    int d = (e < E_RAW) ? dst[e] : e - E_RAW;
    atomicAdd(&counts[d], 1);
}

__global__ __launch_bounds__(1024) void k_scan(
    const int* __restrict__ counts, int* __restrict__ off)
{
    __shared__ int part[1024];
    const int tid = threadIdx.x;
    const int CH = (N_NODES + 1023) / 1024;           // 49
    const int lo = tid * CH;
    const int hi = (lo + CH < N_NODES) ? lo + CH : N_NODES;
    int s = 0;
    for (int i = lo; i < hi; ++i) s += counts[i];
    part[tid] = s;
    __syncthreads();
    for (int ofs = 1; ofs < 1024; ofs <<= 1) {
        int v = (tid >= ofs) ? part[tid - ofs] : 0;
        __syncthreads();
        part[tid] += v;
        __syncthreads();
    }
    int run = part[tid] - s;                          // exclusive base
    for (int i = lo; i < hi; ++i) { off[i] = run; run += counts[i]; }
    if (tid == 1023) off[N_NODES] = part[1023];
}

__global__ __launch_bounds__(256) void k_scatter(
    const int* __restrict__ src, const int* __restrict__ dst,
    const int* __restrict__ off, int* __restrict__ cursor,
    int* __restrict__ esrc)
{
    int e = blockIdx.x * 256 + threadIdx.x;
    if (e >= E_TOT) return;
    int s, d;
    if (e < E_RAW) { s = src[e]; d = dst[e]; } else { s = e - E_RAW; d = s; }
    int pos = off[d] + atomicAdd(&cursor[d], 1);
    esrc[pos] = s;
}

// ---------------------------------------------------------------------------
// K1: h1 = x @ W1 (f32 math) -> stored as bf16; per-head attention dots (f32).
// ---------------------------------------------------------------------------
__global__ __launch_bounds__(256) void k_gemm1(
    const float* __restrict__ x, const float* __restrict__ W1,
    const float* __restrict__ att_src, const float* __restrict__ att_dst,
    unsigned short* __restrict__ h1b, float* __restrict__ as1, float* __restrict__ ad1)
{
    __shared__ float xs[32 * 256];
    const int t = threadIdx.x;
    const int n0 = blockIdx.x * 32;
    for (int i = t; i < 32 * 256; i += 256) {
        int n = n0 + (i >> 8);
        xs[i] = (n < N_NODES) ? x[n * 256 + (i & 255)] : 0.f;
    }
    __syncthreads();
    const int jg = t & 63;
    const int rg = t >> 6;
    const int col0 = jg * 4;
    float acc[8][4];
#pragma unroll
    for (int r = 0; r < 8; ++r)
#pragma unroll
        for (int c = 0; c < 4; ++c) acc[r][c] = 0.f;

    for (int k = 0; k < 256; k += 4) {
        float4 w0 = *(const float4*)&W1[(k + 0) * 256 + col0];
        float4 w1 = *(const float4*)&W1[(k + 1) * 256 + col0];
        float4 w2 = *(const float4*)&W1[(k + 2) * 256 + col0];
        float4 w3 = *(const float4*)&W1[(k + 3) * 256 + col0];
#pragma unroll
        for (int r = 0; r < 8; ++r) {
            float4 xv = *(const float4*)&xs[(rg * 8 + r) * 256 + k];
            acc[r][0] = fmaf(xv.x, w0.x, fmaf(xv.y, w1.x, fmaf(xv.z, w2.x, fmaf(xv.w, w3.x, acc[r][0]))));
            acc[r][1] = fmaf(xv.x, w0.y, fmaf(xv.y, w1.y, fmaf(xv.z, w2.y, fmaf(xv.w, w3.y, acc[r][1]))));
            acc[r][2] = fmaf(xv.x, w0.z, fmaf(xv.y, w1.z, fmaf(xv.z, w2.z, fmaf(xv.w, w3.z, acc[r][2]))));
            acc[r][3] = fmaf(xv.x, w0.w, fmaf(xv.y, w1.w, fmaf(xv.z, w2.w, fmaf(xv.w, w3.w, acc[r][3]))));
        }
    }
    const int head = jg >> 4;
    const int cih  = (jg & 15) * 4;
    float asv[4], adv[4];
#pragma unroll
    for (int c = 0; c < 4; ++c) {
        asv[c] = att_src[head * 64 + cih + c];
        adv[c] = att_dst[head * 64 + cih + c];
    }
#pragma unroll
    for (int r = 0; r < 8; ++r) {
        const int n = n0 + rg * 8 + r;
        float ps = acc[r][0]*asv[0] + acc[r][1]*asv[1] + acc[r][2]*asv[2] + acc[r][3]*asv[3];
        float pd = acc[r][0]*adv[0] + acc[r][1]*adv[1] + acc[r][2]*adv[2] + acc[r][3]*adv[3];
#pragma unroll
        for (int off = 1; off < 16; off <<= 1) {
            ps += __shfl_xor(ps, off);
            pd += __shfl_xor(pd, off);
        }
        if (n < N_NODES) {
            if ((jg & 15) == 0) {
                as1[n * 4 + head] = ps;
                ad1[n * 4 + head] = pd;
            }
            ushort4 pk;
            pk.x = f2bf(acc[r][0]); pk.y = f2bf(acc[r][1]);
            pk.z = f2bf(acc[r][2]); pk.w = f2bf(acc[r][3]);
            *(ushort4*)&h1b[n * 256 + col0] = pk;
        }
    }
}

// ---------------------------------------------------------------------------
// K2: fused softmax + aggregate + bias + ELU for layer 1 (gather, bf16 h1).
// One wave per dst; lane owns cols lane*4..+3 (head = lane>>4). f32 accum.
// ---------------------------------------------------------------------------
__global__ __launch_bounds__(256) void k_gather1(
    const int* __restrict__ esrc, const int* __restrict__ off,
    const float* __restrict__ as1, const float* __restrict__ ad1,
    const unsigned short* __restrict__ h1b, const float* __restrict__ b1,
    float* __restrict__ hmid)
{
    int d    = (blockIdx.x * 256 + threadIdx.x) >> 6;
    int lane = threadIdx.x & 63;
    if (d >= N_NODES) return;
    const int head = lane >> 4;
    const float adv = ad1[d * 4 + head];
    const int e0 = off[d], e1 = off[d + 1];
    float4 acc = make_float4(0.f, 0.f, 0.f, 0.f);
    float dn = 0.f;
    int e = e0;
    for (; e + 1 < e1; e += 2) {
        int s0 = esrc[e], s1 = esrc[e + 1];
        float w0 = __expf(lrelu(as1[s0 * 4 + head] + adv));
        float w1 = __expf(lrelu(as1[s1 * 4 + head] + adv));
        ushort4 u0 = *(const ushort4*)&h1b[s0 * 256 + lane * 4];
        ushort4 u1 = *(const ushort4*)&h1b[s1 * 256 + lane * 4];
        dn += w0 + w1;
        acc.x = fmaf(w0, bf2f(u0.x), fmaf(w1, bf2f(u1.x), acc.x));
        acc.y = fmaf(w0, bf2f(u0.y), fmaf(w1, bf2f(u1.y), acc.y));
        acc.z = fmaf(w0, bf2f(u0.z), fmaf(w1, bf2f(u1.z), acc.z));
        acc.w = fmaf(w0, bf2f(u0.w), fmaf(w1, bf2f(u1.w), acc.w));
    }
    if (e < e1) {
        int s0 = esrc[e];
        float w0 = __expf(lrelu(as1[s0 * 4 + head] + adv));
        ushort4 u0 = *(const ushort4*)&h1b[s0 * 256 + lane * 4];
        dn += w0;
        acc.x = fmaf(w0, bf2f(u0.x), acc.x);
        acc.y = fmaf(w0, bf2f(u0.y), acc.y);
        acc.z = fmaf(w0, bf2f(u0.z), acc.z);
        acc.w = fmaf(w0, bf2f(u0.w), acc.w);
    }
    const float inv = 1.f / (dn + 1e-16f);
    float4 bb = *(const float4*)&b1[lane * 4];
    float o0 = acc.x * inv + bb.x;
    float o1 = acc.y * inv + bb.y;
    float o2 = acc.z * inv + bb.z;
    float o3 = acc.w * inv + bb.w;
    o0 = o0 > 0.f ? o0 : expm1f(o0);
    o1 = o1 > 0.f ? o1 : expm1f(o1);
    o2 = o2 > 0.f ? o2 : expm1f(o2);
    o3 = o3 > 0.f ? o3 : expm1f(o3);
    *(float4*)&hmid[d * 256 + lane * 4] = make_float4(o0, o1, o2, o3);
}

// ---------------------------------------------------------------------------
// K3: h2 = hmid @ W2 (f32 math) -> stored bf16; attention dots f32.
// ---------------------------------------------------------------------------
__global__ __launch_bounds__(256) void k_gemm2(
    const float* __restrict__ h, const float* __restrict__ W2,
    const float* __restrict__ att_src, const float* __restrict__ att_dst,
    unsigned short* __restrict__ h2b, float* __restrict__ as2, float* __restrict__ ad2)
{
    __shared__ float hs[64 * 264];
    const int t = threadIdx.x;
    const int n0 = blockIdx.x * 64;
#pragma unroll
    for (int it = 0; it < 16; ++it) {
        int linear = it * 1024 + t * 4;
        int r = linear >> 8, c = linear & 255;
        int n = n0 + r;
        float4 v = make_float4(0.f, 0.f, 0.f, 0.f);
        if (n < N_NODES) v = *(const float4*)&h[n * 256 + c];
        *(float4*)&hs[r * 264 + c] = v;
    }
    __syncthreads();
    const int jg = t & 15, rg = t >> 4;
    const int col0 = jg * 4;
    float acc[4][4];
#pragma unroll
    for (int r = 0; r < 4; ++r)
#pragma unroll
        for (int c = 0; c < 4; ++c) acc[r][c] = 0.f;

    for (int k = 0; k < 256; k += 4) {
        float4 w0 = *(const float4*)&W2[(k + 0) * 64 + col0];
        float4 w1 = *(const float4*)&W2[(k + 1) * 64 + col0];
        float4 w2 = *(const float4*)&W2[(k + 2) * 64 + col0];
        float4 w3 = *(const float4*)&W2[(k + 3) * 64 + col0];
#pragma unroll
        for (int r = 0; r < 4; ++r) {
            float4 xv = *(const float4*)&hs[(rg + 16 * r) * 264 + k];
            acc[r][0] = fmaf(xv.x, w0.x, fmaf(xv.y, w1.x, fmaf(xv.z, w2.x, fmaf(xv.w, w3.x, acc[r][0]))));
            acc[r][1] = fmaf(xv.x, w0.y, fmaf(xv.y, w1.y, fmaf(xv.z, w2.y, fmaf(xv.w, w3.y, acc[r][1]))));
            acc[r][2] = fmaf(xv.x, w0.z, fmaf(xv.y, w1.z, fmaf(xv.z, w2.z, fmaf(xv.w, w3.z, acc[r][2]))));
            acc[r][3] = fmaf(xv.x, w0.w, fmaf(xv.y, w1.w, fmaf(xv.z, w2.w, fmaf(xv.w, w3.w, acc[r][3]))));
        }
    }
    float asv[4], adv[4];
#pragma unroll
    for (int c = 0; c < 4; ++c) {
        asv[c] = att_src[col0 + c];
        adv[c] = att_dst[col0 + c];
    }
#pragma unroll
    for (int r = 0; r < 4; ++r) {
        const int n = n0 + rg + 16 * r;
        float ps = acc[r][0]*asv[0] + acc[r][1]*asv[1] + acc[r][2]*asv[2] + acc[r][3]*asv[3];
        float pd = acc[r][0]*adv[0] + acc[r][1]*adv[1] + acc[r][2]*adv[2] + acc[r][3]*adv[3];
#pragma unroll
        for (int off = 1; off < 16; off <<= 1) {
            ps += __shfl_xor(ps, off);
            pd += __shfl_xor(pd, off);
        }
        if (n < N_NODES) {
            if (jg == 0) { as2[n] = ps; ad2[n] = pd; }
            ushort4 pk;
            pk.x = f2bf(acc[r][0]); pk.y = f2bf(acc[r][1]);
            pk.z = f2bf(acc[r][2]); pk.w = f2bf(acc[r][3]);
            *(ushort4*)&h2b[n * 64 + col0] = pk;
        }
    }
}

// ---------------------------------------------------------------------------
// K4: fused softmax + aggregate + bias for layer 2 (gather, bf16 h2).
// One wave per dst; lane = col (C=64). Writes d_out directly.
// ---------------------------------------------------------------------------
__global__ __launch_bounds__(256) void k_gather2(
    const int* __restrict__ esrc, const int* __restrict__ off,
    const float* __restrict__ as2, const float* __restrict__ ad2,
    const unsigned short* __restrict__ h2b, const float* __restrict__ b2,
    float* __restrict__ out)
{
    int d    = (blockIdx.x * 256 + threadIdx.x) >> 6;
    int lane = threadIdx.x & 63;
    if (d >= N_NODES) return;
    const float adv = ad2[d];
    const int e0 = off[d], e1 = off[d + 1];
    float acc = 0.f, dn = 0.f;
    int e = e0;
    for (; e + 1 < e1; e += 2) {
        int s0 = esrc[e], s1 = esrc[e + 1];
        float w0 = __expf(lrelu(as2[s0] + adv));
        float w1 = __expf(lrelu(as2[s1] + adv));
        float v0 = bf2f(h2b[s0 * 64 + lane]);
        float v1 = bf2f(h2b[s1 * 64 + lane]);
        dn += w0 + w1;
        acc = fmaf(w0, v0, fmaf(w1, v1, acc));
    }
    if (e < e1) {
        int s0 = esrc[e];
        float w0 = __expf(lrelu(as2[s0] + adv));
        float v0 = bf2f(h2b[s0 * 64 + lane]);
        dn += w0;
        acc = fmaf(w0, v0, acc);
    }
    out[d * 64 + lane] = acc / (dn + 1e-16f) + b2[lane];
}

// ---------------------------------------------------------------------------
// Workspace layout (bytes), total 82,900,000:
//   counts @ 0          200,000  [zeroed]
//   cursor @ 200,000    200,000  [zeroed]
//   off    @ 400,000    200,004
//   as1    @ 700,000    800,000
//   ad1    @ 1,500,000  800,000
//   as2    @ 2,300,000  200,000
//   ad2    @ 2,500,000  200,000
//   esrc   @ 2,700,000  3,400,000
//   h1b    @ 6,100,000  25,600,000 bf16 (dead after gather1; h2b reuses)
//   h2b    @ 6,100,000   6,400,000 bf16
//   hmid   @ 31,700,000 51,200,000 f32
// ---------------------------------------------------------------------------
extern "C" void kernel_launch(void* const* d_in, const int* in_sizes, int n_in,
                              void* d_out, int out_size, void* d_ws, size_t ws_size,
                              hipStream_t stream)
{
    const float* x        = (const float*)d_in[0];
    const int*   ei       = (const int*)d_in[1];
    const float* W1       = (const float*)d_in[2];
    const float* att_src1 = (const float*)d_in[3];
    const float* att_dst1 = (const float*)d_in[4];
    const float* b1       = (const float*)d_in[5];
    const float* W2       = (const float*)d_in[6];
    const float* att_src2 = (const float*)d_in[7];
    const float* att_dst2 = (const float*)d_in[8];
    const float* b2       = (const float*)d_in[9];
    const int* src = ei;
    const int* dst = ei + E_RAW;
    float* out = (float*)d_out;

    char* ws = (char*)d_ws;
    int*            counts = (int*)(ws + 0);
    int*            cursor = (int*)(ws + 200000);
    int*            off    = (int*)(ws + 400000);
    float*          as1    = (float*)(ws + 700000);
    float*          ad1    = (float*)(ws + 1500000);
    float*          as2    = (float*)(ws + 2300000);
    float*          ad2    = (float*)(ws + 2500000);
    int*            esrc   = (int*)(ws + 2700000);
    unsigned short* h1b    = (unsigned short*)(ws + 6100000);
    unsigned short* h2b    = (unsigned short*)(ws + 6100000);  // reuses h1b
    float*          hmid   = (float*)(ws + 31700000);

    hipMemsetAsync(ws, 0, 400000, stream);      // counts + cursor

    const int EB = (E_TOT + 255) / 256;
    k_hist   <<<EB, 256, 0, stream>>>(dst, counts);
    k_scan   <<<1, 1024, 0, stream>>>(counts, off);
    k_scatter<<<EB, 256, 0, stream>>>(src, dst, off, cursor, esrc);

    k_gemm1  <<<1563, 256, 0, stream>>>(x, W1, att_src1, att_dst1, h1b, as1, ad1);
    k_gather1<<<12500, 256, 0, stream>>>(esrc, off, as1, ad1, h1b, b1, hmid);
    k_gemm2  <<<782, 256, 0, stream>>>(hmid, W2, att_src2, att_dst2, h2b, as2, ad2);
    k_gather2<<<12500, 256, 0, stream>>>(esrc, off, as2, ad2, h2b, b2, out);
}

// Round 4
// 336.360 us; speedup vs baseline: 10.1099x; 1.3152x over previous
//
#include <hip/hip_runtime.h>
#include <math.h>

#define N_NODES 50000
#define E_RAW   800000
#define E_TOT   850000
#define NEG_SLOPE 0.2f
#define NBC 196   // scan blocks = ceil(50000/256)

typedef __attribute__((ext_vector_type(8))) short short8;
typedef __attribute__((ext_vector_type(4))) float f32x4;

__device__ __forceinline__ float lrelu(float v) {
    return v >= 0.f ? v : NEG_SLOPE * v;
}
__device__ __forceinline__ unsigned short f2bf(float f) {
    union { float f; unsigned u; } v; v.f = f;
    unsigned r = v.u + 0x7FFF + ((v.u >> 16) & 1);
    return (unsigned short)(r >> 16);
}
__device__ __forceinline__ float bf2f(unsigned short h) {
    union { unsigned u; float f; } v; v.u = ((unsigned)h) << 16;
    return v.f;
}
// column permutation used for h1b storage: position p holds column C(p)
// (16x16 transpose, self-inverse)
__device__ __forceinline__ int C1(int p) { return (p & 15) * 16 + (p >> 4); }
// layer-2 variant (64 cols): position p holds column (p&3)*16 + (p>>2)
__device__ __forceinline__ int C2(int p) { return (p & 3) * 16 + (p >> 2); }

// ---------------------------------------------------------------------------
// CSR build: histogram -> coalesced 3-phase scan -> scatter.
// ---------------------------------------------------------------------------
__global__ __launch_bounds__(256) void k_hist(
    const int* __restrict__ dst, int* __restrict__ counts)
{
    int e = blockIdx.x * 256 + threadIdx.x;
    if (e >= E_TOT) return;
    int d = (e < E_RAW) ? dst[e] : e - E_RAW;
    atomicAdd(&counts[d], 1);
}

__global__ __launch_bounds__(256) void k_scan1(
    const int* __restrict__ counts, int* __restrict__ off, int* __restrict__ bsum)
{
    __shared__ int sh[256];
    int t = threadIdx.x, i = blockIdx.x * 256 + t;
    int c = (i < N_NODES) ? counts[i] : 0;
    sh[t] = c; __syncthreads();
    for (int ofs = 1; ofs < 256; ofs <<= 1) {
        int v = (t >= ofs) ? sh[t - ofs] : 0;
        __syncthreads(); sh[t] += v; __syncthreads();
    }
    if (i < N_NODES) off[i] = sh[t] - c;            // exclusive in-block
    if (t == 255) bsum[blockIdx.x] = sh[255];
}

__global__ __launch_bounds__(256) void k_scan2(int* __restrict__ bsum)
{
    __shared__ int sh[256];
    int t = threadIdx.x;
    int c = (t < NBC) ? bsum[t] : 0;
    sh[t] = c; __syncthreads();
    for (int ofs = 1; ofs < 256; ofs <<= 1) {
        int v = (t >= ofs) ? sh[t - ofs] : 0;
        __syncthreads(); sh[t] += v; __syncthreads();
    }
    if (t < NBC) bsum[t] = sh[t] - c;               // exclusive
}

__global__ __launch_bounds__(256) void k_scan3(
    int* __restrict__ off, const int* __restrict__ bsum)
{
    int i = blockIdx.x * 256 + threadIdx.x;
    if (i < N_NODES) off[i] += bsum[blockIdx.x];
    if (i == 0) off[N_NODES] = E_TOT;
}

__global__ __launch_bounds__(256) void k_scatter(
    const int* __restrict__ src, const int* __restrict__ dst,
    const int* __restrict__ off, int* __restrict__ cursor,
    int* __restrict__ esrc)
{
    int e = blockIdx.x * 256 + threadIdx.x;
    if (e >= E_TOT) return;
    int s, d;
    if (e < E_RAW) { s = src[e]; d = dst[e]; } else { s = e - E_RAW; d = s; }
    int pos = off[d] + atomicAdd(&cursor[d], 1);
    esrc[pos] = s;
}

// ---------------------------------------------------------------------------
// Weight prep: arrange W into MFMA B-fragment order, bf16.
// Wf[( nb*8 + kb )*64 + lane][j] = B[k = kb*32+(lane>>4)*8+j][col = nb*16+(lane&15)]
// For W2, the k axis is pre-permuted by C1 (hmid is stored permuted).
// ---------------------------------------------------------------------------
__global__ __launch_bounds__(256) void k_prepw1(
    const float* __restrict__ W1, unsigned short* __restrict__ Wf1)
{
    int idx = blockIdx.x * 256 + threadIdx.x;       // 0..8191
    int lane = idx & 63, kb = (idx >> 6) & 7, nb = idx >> 9;
    int c = nb * 16 + (lane & 15);
    int k0 = kb * 32 + ((lane >> 4) & 3) * 8;
    short8 pk;
#pragma unroll
    for (int j = 0; j < 8; ++j)
        pk[j] = (short)f2bf(W1[(k0 + j) * 256 + c]);
    *(short8*)&Wf1[idx * 8] = pk;
}

__global__ __launch_bounds__(256) void k_prepw2(
    const float* __restrict__ W2, unsigned short* __restrict__ Wf2)
{
    int idx = blockIdx.x * 256 + threadIdx.x;       // 0..2047
    int lane = idx & 63, kb = (idx >> 6) & 7, nb = idx >> 9;  // nb 0..3
    int c = nb * 16 + (lane & 15);
    int k0 = kb * 32 + ((lane >> 4) & 3) * 8;
    short8 pk;
#pragma unroll
    for (int j = 0; j < 8; ++j) {
        int ktrue = C1(k0 + j);                     // undo hmid permutation
        pk[j] = (short)f2bf(W2[ktrue * 64 + c]);
    }
    *(short8*)&Wf2[idx * 8] = pk;
}

// ---------------------------------------------------------------------------
// GEMM1: h1 = x @ W1, bf16 MFMA 16x16x32, f32 accum. 4 waves/block, 16 rows
// per wave, all 256 cols. A-frags straight from global x (f32->bf16 in reg),
// B-frags from Wf1 (lane-coalesced 16B, L2-resident). Output stored bf16 in
// permuted order: h1b[n*256 + p] = h1[n][C1(p)], 32B/lane contiguous stores.
// ---------------------------------------------------------------------------
__global__ __launch_bounds__(256) void k_gemm1(
    const float* __restrict__ x, const unsigned short* __restrict__ Wf1,
    unsigned short* __restrict__ h1b)
{
    const int t = threadIdx.x;
    const int lane = t & 63;
    const int w = t >> 6;
    const int rbase = blockIdx.x * 64 + w * 16;
    const int rowA = rbase + (lane & 15);
    const int rA = rowA < N_NODES ? rowA : N_NODES - 1;
    const int kg = lane >> 4;                       // 0..3

    f32x4 acc[16];
#pragma unroll
    for (int nb = 0; nb < 16; ++nb) acc[nb] = (f32x4){0.f, 0.f, 0.f, 0.f};

    for (int kb = 0; kb < 8; ++kb) {
        const float* ap = &x[rA * 256 + kb * 32 + kg * 8];
        float4 a0 = *(const float4*)ap;
        float4 a1 = *(const float4*)(ap + 4);
        short8 af;
        af[0] = (short)f2bf(a0.x); af[1] = (short)f2bf(a0.y);
        af[2] = (short)f2bf(a0.z); af[3] = (short)f2bf(a0.w);
        af[4] = (short)f2bf(a1.x); af[5] = (short)f2bf(a1.y);
        af[6] = (short)f2bf(a1.z); af[7] = (short)f2bf(a1.w);
#pragma unroll
        for (int nb = 0; nb < 16; ++nb) {
            short8 bf = *(const short8*)&Wf1[((nb * 8 + kb) * 64 + lane) * 8];
            acc[nb] = __builtin_amdgcn_mfma_f32_16x16x32_bf16(af, bf, acc[nb], 0, 0, 0);
        }
    }
#pragma unroll
    for (int reg = 0; reg < 4; ++reg) {
        int n = rbase + kg * 4 + reg;               // C/D row = (lane>>4)*4+reg
        if (n < N_NODES) {
            short8 lo, hi;
#pragma unroll
            for (int nb = 0; nb < 8; ++nb)  lo[nb] = (short)f2bf(acc[nb][reg]);
#pragma unroll
            for (int nb = 8; nb < 16; ++nb) hi[nb - 8] = (short)f2bf(acc[nb][reg]);
            unsigned short* op = &h1b[n * 256 + (lane & 15) * 16];
            *(short8*)op = lo;
            *(short8*)(op + 8) = hi;
        }
    }
}

// ---------------------------------------------------------------------------
// att1: as1/ad1 dots from permuted h1b. Wave per node; lane reads 4 bf16 at
// positions lane*4..+3 -> all in head (lane&3); att arrays are flat [4*64]
// indexed exactly by column. Reduce over 16 lanes sharing lane&3.
// ---------------------------------------------------------------------------
__global__ __launch_bounds__(256) void k_att1(
    const unsigned short* __restrict__ h1b,
    const float* __restrict__ att_src, const float* __restrict__ att_dst,
    float* __restrict__ as1, float* __restrict__ ad1)
{
    int n    = (blockIdx.x * 256 + threadIdx.x) >> 6;
    int lane = threadIdx.x & 63;
    if (n >= N_NODES) return;
    ushort4 u = *(const ushort4*)&h1b[n * 256 + lane * 4];
    float s = 0.f, d = 0.f;
    unsigned short uv[4] = {u.x, u.y, u.z, u.w};
#pragma unroll
    for (int i = 0; i < 4; ++i) {
        int col = C1(lane * 4 + i);
        float hv = bf2f(uv[i]);
        s = fmaf(hv, att_src[col], s);
        d = fmaf(hv, att_dst[col], d);
    }
#pragma unroll
    for (int ofs = 4; ofs < 64; ofs <<= 1) {
        s += __shfl_xor(s, ofs);
        d += __shfl_xor(d, ofs);
    }
    if (lane < 4) { as1[n * 4 + lane] = s; ad1[n * 4 + lane] = d; }
}

// ---------------------------------------------------------------------------
// gather1: fused softmax+aggregate+bias+ELU, permuted positions flow through.
// Writes hmid as bf16 (feeds gemm2's A directly).
// ---------------------------------------------------------------------------
__global__ __launch_bounds__(256) void k_gather1(
    const int* __restrict__ esrc, const int* __restrict__ off,
    const float* __restrict__ as1, const float* __restrict__ ad1,
    const unsigned short* __restrict__ h1b, const float* __restrict__ b1,
    unsigned short* __restrict__ hmid)
{
    int d    = (blockIdx.x * 256 + threadIdx.x) >> 6;
    int lane = threadIdx.x & 63;
    if (d >= N_NODES) return;
    const int head = lane & 3;                      // head of positions lane*4..+3
    const float adv = ad1[d * 4 + head];
    const int e0 = off[d], e1 = off[d + 1];
    float4 acc = make_float4(0.f, 0.f, 0.f, 0.f);
    float dn = 0.f;
    int e = e0;
    for (; e + 1 < e1; e += 2) {
        int s0 = esrc[e], s1 = esrc[e + 1];
        float w0 = __expf(lrelu(as1[s0 * 4 + head] + adv));
        float w1 = __expf(lrelu(as1[s1 * 4 + head] + adv));
        ushort4 u0 = *(const ushort4*)&h1b[s0 * 256 + lane * 4];
        ushort4 u1 = *(const ushort4*)&h1b[s1 * 256 + lane * 4];
        dn += w0 + w1;
        acc.x = fmaf(w0, bf2f(u0.x), fmaf(w1, bf2f(u1.x), acc.x));
        acc.y = fmaf(w0, bf2f(u0.y), fmaf(w1, bf2f(u1.y), acc.y));
        acc.z = fmaf(w0, bf2f(u0.z), fmaf(w1, bf2f(u1.z), acc.z));
        acc.w = fmaf(w0, bf2f(u0.w), fmaf(w1, bf2f(u1.w), acc.w));
    }
    if (e < e1) {
        int s0 = esrc[e];
        float w0 = __expf(lrelu(as1[s0 * 4 + head] + adv));
        ushort4 u0 = *(const ushort4*)&h1b[s0 * 256 + lane * 4];
        dn += w0;
        acc.x = fmaf(w0, bf2f(u0.x), acc.x);
        acc.y = fmaf(w0, bf2f(u0.y), acc.y);
        acc.z = fmaf(w0, bf2f(u0.z), acc.z);
        acc.w = fmaf(w0, bf2f(u0.w), acc.w);
    }
    const float inv = 1.f / (dn + 1e-16f);
    float o[4] = {acc.x, acc.y, acc.z, acc.w};
    ushort4 pk;
    unsigned short* pko = (unsigned short*)&pk;
#pragma unroll
    for (int i = 0; i < 4; ++i) {
        float v = o[i] * inv + b1[C1(lane * 4 + i)];
        v = v > 0.f ? v : expm1f(v);
        pko[i] = f2bf(v);
    }
    *(ushort4*)&hmid[d * 256 + lane * 4] = pk;
}

// ---------------------------------------------------------------------------
// GEMM2: h2 = hmid @ W2 ([50000,256]@[256,64]), same MFMA structure, nb 0..3.
// A-frags are direct ushort8 loads (hmid already bf16, permuted = matches Wf2).
// h2b stored permuted by C2: ushort4 8B stores.
// ---------------------------------------------------------------------------
__global__ __launch_bounds__(256) void k_gemm2(
    const unsigned short* __restrict__ hmid, const unsigned short* __restrict__ Wf2,
    unsigned short* __restrict__ h2b)
{
    const int t = threadIdx.x;
    const int lane = t & 63;
    const int w = t >> 6;
    const int rbase = blockIdx.x * 64 + w * 16;
    const int rowA = rbase + (lane & 15);
    const int rA = rowA < N_NODES ? rowA : N_NODES - 1;
    const int kg = lane >> 4;

    f32x4 acc[4];
#pragma unroll
    for (int nb = 0; nb < 4; ++nb) acc[nb] = (f32x4){0.f, 0.f, 0.f, 0.f};

    for (int kb = 0; kb < 8; ++kb) {
        short8 af = *(const short8*)&hmid[rA * 256 + kb * 32 + kg * 8];
#pragma unroll
        for (int nb = 0; nb < 4; ++nb) {
            short8 bf = *(const short8*)&Wf2[((nb * 8 + kb) * 64 + lane) * 8];
            acc[nb] = __builtin_amdgcn_mfma_f32_16x16x32_bf16(af, bf, acc[nb], 0, 0, 0);
        }
    }
#pragma unroll
    for (int reg = 0; reg < 4; ++reg) {
        int n = rbase + kg * 4 + reg;
        if (n < N_NODES) {
            ushort4 pk;
            pk.x = f2bf(acc[0][reg]); pk.y = f2bf(acc[1][reg]);
            pk.z = f2bf(acc[2][reg]); pk.w = f2bf(acc[3][reg]);
            *(ushort4*)&h2b[n * 64 + (lane & 15) * 4] = pk;
        }
    }
}

// att2: as2/ad2 from permuted h2b. Wave per node, 1 bf16/lane, full-wave reduce.
__global__ __launch_bounds__(256) void k_att2(
    const unsigned short* __restrict__ h2b,
    const float* __restrict__ att_src, const float* __restrict__ att_dst,
    float* __restrict__ as2, float* __restrict__ ad2)
{
    int n    = (blockIdx.x * 256 + threadIdx.x) >> 6;
    int lane = threadIdx.x & 63;
    if (n >= N_NODES) return;
    float hv = bf2f(h2b[n * 64 + lane]);
    int col = C2(lane);
    float s = hv * att_src[col];
    float d = hv * att_dst[col];
#pragma unroll
    for (int ofs = 1; ofs < 64; ofs <<= 1) {
        s += __shfl_xor(s, ofs);
        d += __shfl_xor(d, ofs);
    }
    if (lane == 0) { as2[n] = s; ad2[n] = d; }
}

// gather2: fused softmax+aggregate+bias for layer 2; writes d_out (un-permuting).
__global__ __launch_bounds__(256) void k_gather2(
    const int* __restrict__ esrc, const int* __restrict__ off,
    const float* __restrict__ as2, const float* __restrict__ ad2,
    const unsigned short* __restrict__ h2b, const float* __restrict__ b2,
    float* __restrict__ out)
{
    int d    = (blockIdx.x * 256 + threadIdx.x) >> 6;
    int lane = threadIdx.x & 63;
    if (d >= N_NODES) return;
    const float adv = ad2[d];
    const int e0 = off[d], e1 = off[d + 1];
    float acc = 0.f, dn = 0.f;
    int e = e0;
    for (; e + 1 < e1; e += 2) {
        int s0 = esrc[e], s1 = esrc[e + 1];
        float w0 = __expf(lrelu(as2[s0] + adv));
        float w1 = __expf(lrelu(as2[s1] + adv));
        float v0 = bf2f(h2b[s0 * 64 + lane]);
        float v1 = bf2f(h2b[s1 * 64 + lane]);
        dn += w0 + w1;
        acc = fmaf(w0, v0, fmaf(w1, v1, acc));
    }
    if (e < e1) {
        int s0 = esrc[e];
        float w0 = __expf(lrelu(as2[s0] + adv));
        float v0 = bf2f(h2b[s0 * 64 + lane]);
        dn += w0;
        acc = fmaf(w0, v0, acc);
    }
    int col = C2(lane);
    out[d * 64 + col] = acc / (dn + 1e-16f) + b2[col];
}

// ---------------------------------------------------------------------------
// Workspace layout (bytes), total ~57.4 MB:
//   counts @ 0          200,000  [zeroed]
//   cursor @ 200,000    200,000  [zeroed]
//   off    @ 400,000    200,004
//   bsum   @ 600,064    800
//   as1    @ 600,896    800,000
//   ad1    @ 1,400,896  800,000
//   as2    @ 2,200,896  200,000
//   ad2    @ 2,400,896  200,000
//   esrc   @ 2,600,896  3,400,000
//   Wf1    @ 6,000,896  131,072
//   Wf2    @ 6,131,968  32,768
//   h1b    @ 6,164,736  25,600,000 bf16 (h2b reuses after gather1)
//   h2b    @ 6,164,736  6,400,000 bf16
//   hmid   @ 31,764,736 25,600,000 bf16
// ---------------------------------------------------------------------------
extern "C" void kernel_launch(void* const* d_in, const int* in_sizes, int n_in,
                              void* d_out, int out_size, void* d_ws, size_t ws_size,
                              hipStream_t stream)
{
    const float* x        = (const float*)d_in[0];
    const int*   ei       = (const int*)d_in[1];
    const float* W1       = (const float*)d_in[2];
    const float* att_src1 = (const float*)d_in[3];
    const float* att_dst1 = (const float*)d_in[4];
    const float* b1       = (const float*)d_in[5];
    const float* W2       = (const float*)d_in[6];
    const float* att_src2 = (const float*)d_in[7];
    const float* att_dst2 = (const float*)d_in[8];
    const float* b2       = (const float*)d_in[9];
    const int* src = ei;
    const int* dst = ei + E_RAW;
    float* out = (float*)d_out;

    char* ws = (char*)d_ws;
    int*            counts = (int*)(ws + 0);
    int*            cursor = (int*)(ws + 200000);
    int*            off    = (int*)(ws + 400000);
    int*            bsum   = (int*)(ws + 600064);
    float*          as1    = (float*)(ws + 600896);
    float*          ad1    = (float*)(ws + 1400896);
    float*          as2    = (float*)(ws + 2200896);
    float*          ad2    = (float*)(ws + 2400896);
    int*            esrc   = (int*)(ws + 2600896);
    unsigned short* Wf1    = (unsigned short*)(ws + 6000896);
    unsigned short* Wf2    = (unsigned short*)(ws + 6131968);
    unsigned short* h1b    = (unsigned short*)(ws + 6164736);
    unsigned short* h2b    = (unsigned short*)(ws + 6164736);   // reuses h1b
    unsigned short* hmid   = (unsigned short*)(ws + 31764736);

    hipMemsetAsync(ws, 0, 400000, stream);      // counts + cursor

    const int EB = (E_TOT + 255) / 256;
    k_prepw1 <<<32, 256, 0, stream>>>(W1, Wf1);
    k_prepw2 <<<8, 256, 0, stream>>>(W2, Wf2);
    k_hist   <<<EB, 256, 0, stream>>>(dst, counts);
    k_scan1  <<<NBC, 256, 0, stream>>>(counts, off, bsum);
    k_scan2  <<<1, 256, 0, stream>>>(bsum);
    k_scan3  <<<NBC, 256, 0, stream>>>(off, bsum);
    k_scatter<<<EB, 256, 0, stream>>>(src, dst, off, cursor, esrc);

    k_gemm1  <<<782, 256, 0, stream>>>(x, Wf1, h1b);
    k_att1   <<<12500, 256, 0, stream>>>(h1b, att_src1, att_dst1, as1, ad1);
    k_gather1<<<12500, 256, 0, stream>>>(esrc, off, as1, ad1, h1b, b1, hmid);
    k_gemm2  <<<782, 256, 0, stream>>>(hmid, Wf2, h2b);
    k_att2   <<<12500, 256, 0, stream>>>(h2b, att_src2, att_dst2, as2, ad2);
    k_gather2<<<12500, 256, 0, stream>>>(esrc, off, as2, ad2, h2b, b2, out);
}

// Round 5
// 265.461 us; speedup vs baseline: 12.8100x; 1.2671x over previous
//
#include <hip/hip_runtime.h>
#include <math.h>

#define N_NODES 50000
#define E_RAW   800000
#define E_TOT   850000
#define NEG_SLOPE 0.2f
#define NBC 196   // scan blocks = ceil(50000/256)

typedef __attribute__((ext_vector_type(8))) short short8;
typedef __attribute__((ext_vector_type(4))) float f32x4;

__device__ __forceinline__ float lrelu(float v) {
    return v >= 0.f ? v : NEG_SLOPE * v;
}
__device__ __forceinline__ unsigned short f2bf(float f) {
    union { float f; unsigned u; } v; v.f = f;
    unsigned r = v.u + 0x7FFF + ((v.u >> 16) & 1);
    return (unsigned short)(r >> 16);
}
__device__ __forceinline__ float bf2f(unsigned short h) {
    union { unsigned u; float f; } v; v.u = ((unsigned)h) << 16;
    return v.f;
}
// h1b position p holds column C1(p) (16x16 transpose, self-inverse)
__device__ __forceinline__ int C1(int p) { return (p & 15) * 16 + (p >> 4); }
// h2b position p holds column C2(p)
__device__ __forceinline__ int C2(int p) { return (p & 3) * 16 + (p >> 2); }

// ---------------------------------------------------------------------------
// CSR build: histogram -> coalesced 3-phase scan -> scatter.
// ---------------------------------------------------------------------------
__global__ __launch_bounds__(256) void k_hist(
    const int* __restrict__ dst, int* __restrict__ counts)
{
    int e = blockIdx.x * 256 + threadIdx.x;
    if (e >= E_TOT) return;
    int d = (e < E_RAW) ? dst[e] : e - E_RAW;
    atomicAdd(&counts[d], 1);
}

__global__ __launch_bounds__(256) void k_scan1(
    const int* __restrict__ counts, int* __restrict__ off, int* __restrict__ bsum)
{
    __shared__ int sh[256];
    int t = threadIdx.x, i = blockIdx.x * 256 + t;
    int c = (i < N_NODES) ? counts[i] : 0;
    sh[t] = c; __syncthreads();
    for (int ofs = 1; ofs < 256; ofs <<= 1) {
        int v = (t >= ofs) ? sh[t - ofs] : 0;
        __syncthreads(); sh[t] += v; __syncthreads();
    }
    if (i < N_NODES) off[i] = sh[t] - c;
    if (t == 255) bsum[blockIdx.x] = sh[255];
}

__global__ __launch_bounds__(256) void k_scan2(int* __restrict__ bsum)
{
    __shared__ int sh[256];
    int t = threadIdx.x;
    int c = (t < NBC) ? bsum[t] : 0;
    sh[t] = c; __syncthreads();
    for (int ofs = 1; ofs < 256; ofs <<= 1) {
        int v = (t >= ofs) ? sh[t - ofs] : 0;
        __syncthreads(); sh[t] += v; __syncthreads();
    }
    if (t < NBC) bsum[t] = sh[t] - c;
}

__global__ __launch_bounds__(256) void k_scan3(
    int* __restrict__ off, const int* __restrict__ bsum)
{
    int i = blockIdx.x * 256 + threadIdx.x;
    if (i < N_NODES) off[i] += bsum[blockIdx.x];
    if (i == 0) off[N_NODES] = E_TOT;
}

__global__ __launch_bounds__(256) void k_scatter(
    const int* __restrict__ src, const int* __restrict__ dst,
    const int* __restrict__ off, int* __restrict__ cursor,
    int* __restrict__ esrc)
{
    int e = blockIdx.x * 256 + threadIdx.x;
    if (e >= E_TOT) return;
    int s, d;
    if (e < E_RAW) { s = src[e]; d = dst[e]; } else { s = e - E_RAW; d = s; }
    int pos = off[d] + atomicAdd(&cursor[d], 1);
    esrc[pos] = s;
}

// ---------------------------------------------------------------------------
// Weight prep into MFMA B-fragment order (bf16):
// Wf[(nbg*8+kb)*64+lane][j] = B[k=kb*32+(lane>>4)*8+j][col=nbg*16+(lane&15)]
// W2's k axis pre-permuted by C1 (hmid stored permuted).
// ---------------------------------------------------------------------------
__global__ __launch_bounds__(256) void k_prepw1(
    const float* __restrict__ W1, unsigned short* __restrict__ Wf1)
{
    int idx = blockIdx.x * 256 + threadIdx.x;       // 0..8191
    int lane = idx & 63, kb = (idx >> 6) & 7, nb = idx >> 9;
    int c = nb * 16 + (lane & 15);
    int k0 = kb * 32 + ((lane >> 4) & 3) * 8;
    short8 pk;
#pragma unroll
    for (int j = 0; j < 8; ++j)
        pk[j] = (short)f2bf(W1[(k0 + j) * 256 + c]);
    *(short8*)&Wf1[idx * 8] = pk;
}

__global__ __launch_bounds__(256) void k_prepw2(
    const float* __restrict__ W2, unsigned short* __restrict__ Wf2)
{
    int idx = blockIdx.x * 256 + threadIdx.x;       // 0..2047
    int lane = idx & 63, kb = (idx >> 6) & 7, nb = idx >> 9;
    int c = nb * 16 + (lane & 15);
    int k0 = kb * 32 + ((lane >> 4) & 3) * 8;
    short8 pk;
#pragma unroll
    for (int j = 0; j < 8; ++j) {
        int ktrue = C1(k0 + j);
        pk[j] = (short)f2bf(W2[ktrue * 64 + c]);
    }
    *(short8*)&Wf2[idx * 8] = pk;
}

// ---------------------------------------------------------------------------
// GEMM1: h1 = x @ W1. 3125 blocks x 4 waves; block owns 16 rows (exact:
// 50000 = 3125*16, no bounds checks). Wave w owns nb = w*4..w*4+3, i.e.
// exactly head w. Register double-buffer of A (f32->bf16) and B frags
// across kb. Fused att-dot epilogue (16-lane shfl reduce), no LDS.
// ---------------------------------------------------------------------------
__global__ __launch_bounds__(256) void k_gemm1(
    const float* __restrict__ x, const unsigned short* __restrict__ Wf1,
    const float* __restrict__ att_src, const float* __restrict__ att_dst,
    unsigned short* __restrict__ h1b, float* __restrict__ as1, float* __restrict__ ad1)
{
    const int t = threadIdx.x;
    const int lane = t & 63;
    const int w = t >> 6;                           // wave = head = nb group
    const int rbase = blockIdx.x * 16;
    const int q  = lane & 15;                       // A row-in-tile / frag col
    const int kg = lane >> 4;                       // k-subgroup 0..3
    const int rowA = rbase + q;

    f32x4 acc[4];
#pragma unroll
    for (int nb = 0; nb < 4; ++nb) acc[nb] = (f32x4){0.f, 0.f, 0.f, 0.f};

    short8 b[2][4];
    float4 a0, a1, a0n, a1n;
    {
        const float* ap = &x[rowA * 256 + kg * 8];
        a0 = *(const float4*)ap;
        a1 = *(const float4*)(ap + 4);
#pragma unroll
        for (int nb = 0; nb < 4; ++nb)
            b[0][nb] = *(const short8*)&Wf1[(((w * 4 + nb) * 8 + 0) * 64 + lane) * 8];
    }
#pragma unroll
    for (int kb = 0; kb < 8; ++kb) {
        if (kb < 7) {
            const float* ap = &x[rowA * 256 + (kb + 1) * 32 + kg * 8];
            a0n = *(const float4*)ap;
            a1n = *(const float4*)(ap + 4);
#pragma unroll
            for (int nb = 0; nb < 4; ++nb)
                b[(kb + 1) & 1][nb] =
                    *(const short8*)&Wf1[(((w * 4 + nb) * 8 + kb + 1) * 64 + lane) * 8];
        }
        short8 af;
        af[0] = (short)f2bf(a0.x); af[1] = (short)f2bf(a0.y);
        af[2] = (short)f2bf(a0.z); af[3] = (short)f2bf(a0.w);
        af[4] = (short)f2bf(a1.x); af[5] = (short)f2bf(a1.y);
        af[6] = (short)f2bf(a1.z); af[7] = (short)f2bf(a1.w);
#pragma unroll
        for (int nb = 0; nb < 4; ++nb)
            acc[nb] = __builtin_amdgcn_mfma_f32_16x16x32_bf16(af, b[kb & 1][nb], acc[nb], 0, 0, 0);
        if (kb < 7) { a0 = a0n; a1 = a1n; }
    }

    // store: position p = q*16 + w*4 + nb  holds col (w*4+nb)*16 + q = C1(p)
#pragma unroll
    for (int reg = 0; reg < 4; ++reg) {
        int n = rbase + kg * 4 + reg;               // C/D row = kg*4+reg
        ushort4 pk;
        pk.x = f2bf(acc[0][reg]); pk.y = f2bf(acc[1][reg]);
        pk.z = f2bf(acc[2][reg]); pk.w = f2bf(acc[3][reg]);
        *(ushort4*)&h1b[n * 256 + q * 16 + w * 4] = pk;
    }
    // fused attention dots for head w
    float asv[4], adv[4];
#pragma unroll
    for (int nb = 0; nb < 4; ++nb) {
        int col = (w * 4 + nb) * 16 + q;
        asv[nb] = att_src[col];
        adv[nb] = att_dst[col];
    }
#pragma unroll
    for (int reg = 0; reg < 4; ++reg) {
        float s = acc[0][reg]*asv[0] + acc[1][reg]*asv[1] + acc[2][reg]*asv[2] + acc[3][reg]*asv[3];
        float d = acc[0][reg]*adv[0] + acc[1][reg]*adv[1] + acc[2][reg]*adv[2] + acc[3][reg]*adv[3];
#pragma unroll
        for (int ofs = 1; ofs < 16; ofs <<= 1) {
            s += __shfl_xor(s, ofs);
            d += __shfl_xor(d, ofs);
        }
        if (q == 0) {
            int n = rbase + kg * 4 + reg;
            as1[n * 4 + w] = s;
            ad1[n * 4 + w] = d;
        }
    }
}

// ---------------------------------------------------------------------------
// gather1: fused softmax + aggregate + bias + ELU (4x unrolled for MLP).
// ---------------------------------------------------------------------------
__global__ __launch_bounds__(256) void k_gather1(
    const int* __restrict__ esrc, const int* __restrict__ off,
    const float* __restrict__ as1, const float* __restrict__ ad1,
    const unsigned short* __restrict__ h1b, const float* __restrict__ b1,
    unsigned short* __restrict__ hmid)
{
    int d    = (blockIdx.x * 256 + threadIdx.x) >> 6;
    int lane = threadIdx.x & 63;
    if (d >= N_NODES) return;
    const int head = lane & 3;
    const float adv = ad1[d * 4 + head];
    const int e0 = off[d], e1 = off[d + 1];
    float4 acc = make_float4(0.f, 0.f, 0.f, 0.f);
    float dn = 0.f;
    int e = e0;
    for (; e + 3 < e1; e += 4) {
        int s0 = esrc[e], s1 = esrc[e + 1], s2 = esrc[e + 2], s3 = esrc[e + 3];
        float w0 = __expf(lrelu(as1[s0 * 4 + head] + adv));
        float w1 = __expf(lrelu(as1[s1 * 4 + head] + adv));
        float w2 = __expf(lrelu(as1[s2 * 4 + head] + adv));
        float w3 = __expf(lrelu(as1[s3 * 4 + head] + adv));
        ushort4 u0 = *(const ushort4*)&h1b[s0 * 256 + lane * 4];
        ushort4 u1 = *(const ushort4*)&h1b[s1 * 256 + lane * 4];
        ushort4 u2 = *(const ushort4*)&h1b[s2 * 256 + lane * 4];
        ushort4 u3 = *(const ushort4*)&h1b[s3 * 256 + lane * 4];
        dn += (w0 + w1) + (w2 + w3);
        acc.x = fmaf(w0, bf2f(u0.x), fmaf(w1, bf2f(u1.x), fmaf(w2, bf2f(u2.x), fmaf(w3, bf2f(u3.x), acc.x))));
        acc.y = fmaf(w0, bf2f(u0.y), fmaf(w1, bf2f(u1.y), fmaf(w2, bf2f(u2.y), fmaf(w3, bf2f(u3.y), acc.y))));
        acc.z = fmaf(w0, bf2f(u0.z), fmaf(w1, bf2f(u1.z), fmaf(w2, bf2f(u2.z), fmaf(w3, bf2f(u3.z), acc.z))));
        acc.w = fmaf(w0, bf2f(u0.w), fmaf(w1, bf2f(u1.w), fmaf(w2, bf2f(u2.w), fmaf(w3, bf2f(u3.w), acc.w))));
    }
    for (; e < e1; ++e) {
        int s0 = esrc[e];
        float w0 = __expf(lrelu(as1[s0 * 4 + head] + adv));
        ushort4 u0 = *(const ushort4*)&h1b[s0 * 256 + lane * 4];
        dn += w0;
        acc.x = fmaf(w0, bf2f(u0.x), acc.x);
        acc.y = fmaf(w0, bf2f(u0.y), acc.y);
        acc.z = fmaf(w0, bf2f(u0.z), acc.z);
        acc.w = fmaf(w0, bf2f(u0.w), acc.w);
    }
    const float inv = 1.f / (dn + 1e-16f);
    float o[4] = {acc.x, acc.y, acc.z, acc.w};
    ushort4 pk;
    unsigned short* pko = (unsigned short*)&pk;
#pragma unroll
    for (int i = 0; i < 4; ++i) {
        float v = o[i] * inv + b1[C1(lane * 4 + i)];
        v = v > 0.f ? v : expm1f(v);
        pko[i] = f2bf(v);
    }
    *(ushort4*)&hmid[d * 256 + lane * 4] = pk;
}

// ---------------------------------------------------------------------------
// GEMM2: h2 = hmid @ W2 ([50000,256]@[256,64]); 64 rows/block, 4 waves of
// 16 rows, nb 0..3 each; register double-buffer; fused att2 epilogue.
// ---------------------------------------------------------------------------
__global__ __launch_bounds__(256) void k_gemm2(
    const unsigned short* __restrict__ hmid, const unsigned short* __restrict__ Wf2,
    const float* __restrict__ att_src, const float* __restrict__ att_dst,
    unsigned short* __restrict__ h2b, float* __restrict__ as2, float* __restrict__ ad2)
{
    const int t = threadIdx.x;
    const int lane = t & 63;
    const int w = t >> 6;
    const int rbase = blockIdx.x * 64 + w * 16;
    const int q  = lane & 15;
    const int kg = lane >> 4;
    const int rowA = rbase + q;
    const int rA = rowA < N_NODES ? rowA : N_NODES - 1;

    f32x4 acc[4];
#pragma unroll
    for (int nb = 0; nb < 4; ++nb) acc[nb] = (f32x4){0.f, 0.f, 0.f, 0.f};

    short8 b[2][4];
    short8 af, afn;
    af = *(const short8*)&hmid[rA * 256 + kg * 8];
#pragma unroll
    for (int nb = 0; nb < 4; ++nb)
        b[0][nb] = *(const short8*)&Wf2[((nb * 8 + 0) * 64 + lane) * 8];
#pragma unroll
    for (int kb = 0; kb < 8; ++kb) {
        if (kb < 7) {
            afn = *(const short8*)&hmid[rA * 256 + (kb + 1) * 32 + kg * 8];
#pragma unroll
            for (int nb = 0; nb < 4; ++nb)
                b[(kb + 1) & 1][nb] = *(const short8*)&Wf2[((nb * 8 + kb + 1) * 64 + lane) * 8];
        }
#pragma unroll
        for (int nb = 0; nb < 4; ++nb)
            acc[nb] = __builtin_amdgcn_mfma_f32_16x16x32_bf16(af, b[kb & 1][nb], acc[nb], 0, 0, 0);
        if (kb < 7) af = afn;
    }

    float asv[4], adv[4];
#pragma unroll
    for (int nb = 0; nb < 4; ++nb) {
        int col = nb * 16 + q;
        asv[nb] = att_src[col];
        adv[nb] = att_dst[col];
    }
#pragma unroll
    for (int reg = 0; reg < 4; ++reg) {
        int n = rbase + kg * 4 + reg;
        bool ok = n < N_NODES;
        if (ok) {
            ushort4 pk;
            pk.x = f2bf(acc[0][reg]); pk.y = f2bf(acc[1][reg]);
            pk.z = f2bf(acc[2][reg]); pk.w = f2bf(acc[3][reg]);
            *(ushort4*)&h2b[n * 64 + q * 4] = pk;
        }
        float s = acc[0][reg]*asv[0] + acc[1][reg]*asv[1] + acc[2][reg]*asv[2] + acc[3][reg]*asv[3];
        float d = acc[0][reg]*adv[0] + acc[1][reg]*adv[1] + acc[2][reg]*adv[2] + acc[3][reg]*adv[3];
#pragma unroll
        for (int ofs = 1; ofs < 16; ofs <<= 1) {
            s += __shfl_xor(s, ofs);
            d += __shfl_xor(d, ofs);
        }
        if (ok && q == 0) { as2[n] = s; ad2[n] = d; }
    }
}

// ---------------------------------------------------------------------------
// gather2: fused softmax + aggregate + bias (4x unrolled); writes d_out.
// ---------------------------------------------------------------------------
__global__ __launch_bounds__(256) void k_gather2(
    const int* __restrict__ esrc, const int* __restrict__ off,
    const float* __restrict__ as2, const float* __restrict__ ad2,
    const unsigned short* __restrict__ h2b, const float* __restrict__ b2,
    float* __restrict__ out)
{
    int d    = (blockIdx.x * 256 + threadIdx.x) >> 6;
    int lane = threadIdx.x & 63;
    if (d >= N_NODES) return;
    const float adv = ad2[d];
    const int e0 = off[d], e1 = off[d + 1];
    float acc = 0.f, dn = 0.f;
    int e = e0;
    for (; e + 3 < e1; e += 4) {
        int s0 = esrc[e], s1 = esrc[e + 1], s2 = esrc[e + 2], s3 = esrc[e + 3];
        float w0 = __expf(lrelu(as2[s0] + adv));
        float w1 = __expf(lrelu(as2[s1] + adv));
        float w2 = __expf(lrelu(as2[s2] + adv));
        float w3 = __expf(lrelu(as2[s3] + adv));
        float v0 = bf2f(h2b[s0 * 64 + lane]);
        float v1 = bf2f(h2b[s1 * 64 + lane]);
        float v2 = bf2f(h2b[s2 * 64 + lane]);
        float v3 = bf2f(h2b[s3 * 64 + lane]);
        dn += (w0 + w1) + (w2 + w3);
        acc = fmaf(w0, v0, fmaf(w1, v1, fmaf(w2, v2, fmaf(w3, v3, acc))));
    }
    for (; e < e1; ++e) {
        int s0 = esrc[e];
        float w0 = __expf(lrelu(as2[s0] + adv));
        float v0 = bf2f(h2b[s0 * 64 + lane]);
        dn += w0;
        acc = fmaf(w0, v0, acc);
    }
    int col = C2(lane);
    out[d * 64 + col] = acc / (dn + 1e-16f) + b2[col];
}

// ---------------------------------------------------------------------------
// Workspace layout (bytes), total ~57.4 MB (unchanged from round 4).
// ---------------------------------------------------------------------------
extern "C" void kernel_launch(void* const* d_in, const int* in_sizes, int n_in,
                              void* d_out, int out_size, void* d_ws, size_t ws_size,
                              hipStream_t stream)
{
    const float* x        = (const float*)d_in[0];
    const int*   ei       = (const int*)d_in[1];
    const float* W1       = (const float*)d_in[2];
    const float* att_src1 = (const float*)d_in[3];
    const float* att_dst1 = (const float*)d_in[4];
    const float* b1       = (const float*)d_in[5];
    const float* W2       = (const float*)d_in[6];
    const float* att_src2 = (const float*)d_in[7];
    const float* att_dst2 = (const float*)d_in[8];
    const float* b2       = (const float*)d_in[9];
    const int* src = ei;
    const int* dst = ei + E_RAW;
    float* out = (float*)d_out;

    char* ws = (char*)d_ws;
    int*            counts = (int*)(ws + 0);
    int*            cursor = (int*)(ws + 200000);
    int*            off    = (int*)(ws + 400000);
    int*            bsum   = (int*)(ws + 600064);
    float*          as1    = (float*)(ws + 600896);
    float*          ad1    = (float*)(ws + 1400896);
    float*          as2    = (float*)(ws + 2200896);
    float*          ad2    = (float*)(ws + 2400896);
    int*            esrc   = (int*)(ws + 2600896);
    unsigned short* Wf1    = (unsigned short*)(ws + 6000896);
    unsigned short* Wf2    = (unsigned short*)(ws + 6131968);
    unsigned short* h1b    = (unsigned short*)(ws + 6164736);
    unsigned short* h2b    = (unsigned short*)(ws + 6164736);   // reuses h1b
    unsigned short* hmid   = (unsigned short*)(ws + 31764736);

    hipMemsetAsync(ws, 0, 400000, stream);      // counts + cursor

    const int EB = (E_TOT + 255) / 256;
    k_prepw1 <<<32, 256, 0, stream>>>(W1, Wf1);
    k_prepw2 <<<8, 256, 0, stream>>>(W2, Wf2);
    k_hist   <<<EB, 256, 0, stream>>>(dst, counts);
    k_scan1  <<<NBC, 256, 0, stream>>>(counts, off, bsum);
    k_scan2  <<<1, 256, 0, stream>>>(bsum);
    k_scan3  <<<NBC, 256, 0, stream>>>(off, bsum);
    k_scatter<<<EB, 256, 0, stream>>>(src, dst, off, cursor, esrc);

    k_gemm1  <<<3125, 256, 0, stream>>>(x, Wf1, att_src1, att_dst1, h1b, as1, ad1);
    k_gather1<<<12500, 256, 0, stream>>>(esrc, off, as1, ad1, h1b, b1, hmid);
    k_gemm2  <<<782, 256, 0, stream>>>(hmid, Wf2, att_src2, att_dst2, h2b, as2, ad2);
    k_gather2<<<12500, 256, 0, stream>>>(esrc, off, as2, ad2, h2b, b2, out);
}